// Round 1
// baseline (273.294 us; speedup 1.0000x reference)
//
#include <hip/hip_runtime.h>
#include <hip/hip_bf16.h>

#define N_NODES 50000
#define N_EDGES 800000
#define IN_DIM 128
#define HIDDEN 128
#define OUT_DIM 40
#define G_STRIDE 64                                       // padded g row (128B line)

#define SCAN_BS 1024
#define SCAN_BLOCKS ((N_NODES + SCAN_BS - 1) / SCAN_BS)   // 49

#define N_BUCKETS 8
#define BUCKET_NODES (N_NODES / N_BUCKETS)                // 6250
#define HIST_STRIDE 50176                                 // line-aligned copy stride

#define SC_CHUNK 2048                                     // edges per scatter chunk
#define SC_CHUNKS ((N_EDGES + SC_CHUNK - 1) / SC_CHUNK)   // 391

#define HIST_BLOCKS (N_EDGES / 256)                       // 3125
#define G1_BLOCKS ((N_NODES + 63) / 64)                   // 782

struct __align__(8) Edge { int s; float w; };

typedef __attribute__((ext_vector_type(8))) short bf16x8;   // MFMA A/B frag (4 VGPR)
typedef __attribute__((ext_vector_type(4))) float f32x4;    // MFMA C/D frag

// fp32 -> bf16 bits with round-to-nearest-even
__device__ __forceinline__ unsigned f32_to_bf16_bits(float f) {
    unsigned u = __float_as_uint(f);
    return (u + 0x7FFFu + ((u >> 16) & 1u)) >> 16;
}

// ---- 1) fused hist + gemm1: hist blocks (0..3124) build the XCD-private
// ranked histogram; gemm1 blocks (3125..3906) compute y = x @ W1 via MFMA.
// The two are dependency-independent, so they co-run in one dispatch and
// gemm1's MFMA work hides under hist's atomic latency.
__global__ __launch_bounds__(256) void hist_gemm1(const int* __restrict__ dst,
                                                  int* __restrict__ hist8,
                                                  int* __restrict__ erank,
                                                  const float* __restrict__ x,
                                                  const float* __restrict__ W1,
                                                  __hip_bfloat16* __restrict__ y)
{
    __shared__ bf16x8 w1s[2048];                  // 32 KB (gemm1 blocks only)
    int bid = blockIdx.x;

    if (bid < HIST_BLOCKS) {
        // -------- hist path --------
        int i = bid * 256 + threadIdx.x;          // exact: 3125*256 = 800000
        int copy = bid & (N_BUCKETS - 1);
        erank[i] = atomicAdd(&hist8[copy * HIST_STRIDE + dst[i]], 1);
        return;
    }

    // -------- gemm1 path: y = x @ W1 (v_mfma_f32_16x16x32_bf16) --------
    int gb = bid - HIST_BLOCKS;
    int t = threadIdx.x;
    for (int f = t; f < 2048; f += 256) {         // 8 frags per thread
        int lane = f & 63;
        int nt = (f >> 6) & 7;
        int ks = f >> 9;
        int m = lane & 15, quad = lane >> 4;
        bf16x8 frag;
        #pragma unroll
        for (int j = 0; j < 8; ++j) {
            int k = ks * 32 + quad * 8 + j;
            frag[j] = (short)f32_to_bf16_bits(W1[k * HIDDEN + nt * 16 + m]);
        }
        w1s[f] = frag;
    }
    __syncthreads();

    int wv = t >> 6;
    int lane = t & 63;
    int m = lane & 15, quad = lane >> 4;
    int row0 = gb * 64 + wv * 16;
    int arow = row0 + m;
    if (arow >= N_NODES) arow = N_NODES - 1;      // clamp loads; stores guarded

    bf16x8 afrag[4];
    #pragma unroll
    for (int ks = 0; ks < 4; ++ks) {
        const float4* xp = (const float4*)(x + (long long)arow * IN_DIM + ks * 32 + quad * 8);
        float4 a0 = xp[0], a1 = xp[1];
        afrag[ks][0] = (short)f32_to_bf16_bits(a0.x);
        afrag[ks][1] = (short)f32_to_bf16_bits(a0.y);
        afrag[ks][2] = (short)f32_to_bf16_bits(a0.z);
        afrag[ks][3] = (short)f32_to_bf16_bits(a0.w);
        afrag[ks][4] = (short)f32_to_bf16_bits(a1.x);
        afrag[ks][5] = (short)f32_to_bf16_bits(a1.y);
        afrag[ks][6] = (short)f32_to_bf16_bits(a1.z);
        afrag[ks][7] = (short)f32_to_bf16_bits(a1.w);
    }

    f32x4 acc[8];
    #pragma unroll
    for (int nt = 0; nt < 8; ++nt) acc[nt] = (f32x4){0.f, 0.f, 0.f, 0.f};

    #pragma unroll
    for (int ks = 0; ks < 4; ++ks) {
        #pragma unroll
        for (int nt = 0; nt < 8; ++nt) {
            bf16x8 bfrag = w1s[(ks * 8 + nt) * 64 + lane];
            acc[nt] = __builtin_amdgcn_mfma_f32_16x16x32_bf16(afrag[ks], bfrag, acc[nt], 0, 0, 0);
        }
    }

    #pragma unroll
    for (int nt = 0; nt < 8; ++nt) {
        #pragma unroll
        for (int r = 0; r < 4; ++r) {
            int rrow = row0 + quad * 4 + r;
            if (rrow < N_NODES)
                y[(long long)rrow * HIDDEN + nt * 16 + m] = __float2bfloat16(acc[nt][r]);
        }
    }
}

// ---- 2a) convert 8 copies -> per-copy exclusive offsets (in place),
// total into cnt, plus per-block partial sums for the scan ----------------
__global__ __launch_bounds__(SCAN_BS) void scan_partial(int* __restrict__ hist8,
                                                        int* __restrict__ cnt,
                                                        int* __restrict__ block_sums)
{
    __shared__ int red[SCAN_BS / 64];
    int i = blockIdx.x * SCAN_BS + threadIdx.x;
    int total = 0;
    if (i < N_NODES) {
        int off = 0;
        #pragma unroll
        for (int c = 0; c < N_BUCKETS; ++c) {
            int h = hist8[c * HIST_STRIDE + i];
            hist8[c * HIST_STRIDE + i] = off;     // exclusive prefix over copies
            off += h;
        }
        total = off;
        cnt[i] = total;
    }
    int s = total;
    for (int off = 32; off > 0; off >>= 1) s += __shfl_down(s, off, 64);
    int wave = threadIdx.x >> 6, lane = threadIdx.x & 63;
    if (lane == 0) red[wave] = s;
    __syncthreads();
    if (threadIdx.x == 0) {
        int tt = 0;
        #pragma unroll
        for (int wv = 0; wv < SCAN_BS / 64; ++wv) tt += red[wv];
        block_sums[blockIdx.x] = tt;
    }
}

// ---- 2b) block-local exclusive scan; inline prefix over raw block_sums ----
__global__ __launch_bounds__(SCAN_BS) void scan_final(const int* __restrict__ cnt,
                                                      const int* __restrict__ block_sums,
                                                      int* __restrict__ row_ptr)
{
    __shared__ int tmp[SCAN_BS];
    __shared__ int blk_off;
    int t = threadIdx.x;
    int i = blockIdx.x * SCAN_BS + t;
    if (t == 0) {
        int s = 0;
        for (int j = 0; j < (int)blockIdx.x; ++j) s += block_sums[j];
        blk_off = s;
        if (blockIdx.x == 0) row_ptr[N_NODES] = N_EDGES;
    }
    int v = (i < N_NODES) ? cnt[i] : 0;
    tmp[t] = v;
    __syncthreads();
    for (int off = 1; off < SCAN_BS; off <<= 1) {
        int u = (t >= off) ? tmp[t - off] : 0;
        __syncthreads();
        tmp[t] += u;
        __syncthreads();
    }
    if (i < N_NODES) row_ptr[i] = tmp[t] - v + blk_off;
}

// ---- 3) scatter_det: deterministic bucket-filtered placement, NO atomics.
// pos = row_ptr[d] + off8[copy(i)][d] + erank[i]; bucket q = blockIdx&7 owns
// the destination slice (one XCD) so the 8B writes merge in its L2.
__global__ __launch_bounds__(256) void scatter_det(const int* __restrict__ src,
                                                   const int* __restrict__ dst,
                                                   const float* __restrict__ w,
                                                   const int* __restrict__ hist8,
                                                   const int* __restrict__ erank,
                                                   const int* __restrict__ row_ptr,
                                                   Edge* __restrict__ edges)
{
    int q     = blockIdx.x & (N_BUCKETS - 1);
    int chunk = blockIdx.x >> 3;                  // 0..390
    int base  = chunk * SC_CHUNK;
    int lo = q * BUCKET_NODES;
    int hi = lo + BUCKET_NODES;
    #pragma unroll
    for (int r = 0; r < SC_CHUNK / 256; ++r) {
        int i = base + r * 256 + threadIdx.x;
        if (i < N_EDGES) {
            int d = dst[i];
            if (d >= lo && d < hi) {
                int copy = (i >> 8) & (N_BUCKETS - 1);   // == hist's blockIdx&7
                int pos = row_ptr[d] + hist8[copy * HIST_STRIDE + d] + erank[i];
                Edge ed; ed.s = src[i]; ed.w = w[i];
                edges[pos] = ed;
            }
        }
    }
}

// ---- 4) fused spmm1 + gemm2: h1 = relu(A @ y + b1) stays in LDS (f32),
// g = h1 @ W2 computed in the same block. Eliminates the h1 global
// round-trip (25.6 MB) and one dispatch. g rows padded to 64 cols so
// spmm2's per-edge gather is exactly one aligned 128B line.
__global__ __launch_bounds__(256) void spmm1_gemm2(const int* __restrict__ row_ptr,
                                                   const Edge* __restrict__ edges,
                                                   const __hip_bfloat16* __restrict__ y,
                                                   const float* __restrict__ b1,
                                                   const float* __restrict__ W2,
                                                   __hip_bfloat16* __restrict__ g)
{
    __shared__ float hs[4][HIDDEN];               // 2 KB, f32 (better precision)
    int wv = threadIdx.x >> 6;
    int lane = threadIdx.x & 63;
    int node = blockIdx.x * 4 + wv;               // grid exact: 12500*4 = 50000
    int beg = row_ptr[node];
    int end = row_ptr[node + 1];
    const __hip_bfloat162* yv = (const __hip_bfloat162*)y;
    float ax = 0.f, ay = 0.f;
    int j = beg;
    for (; j + 3 < end; j += 4) {
        Edge e0 = edges[j];
        Edge e1 = edges[j + 1];
        Edge e2 = edges[j + 2];
        Edge e3 = edges[j + 3];
        __hip_bfloat162 v0 = yv[(long long)e0.s * 64 + lane];
        __hip_bfloat162 v1 = yv[(long long)e1.s * 64 + lane];
        __hip_bfloat162 v2 = yv[(long long)e2.s * 64 + lane];
        __hip_bfloat162 v3 = yv[(long long)e3.s * 64 + lane];
        ax = fmaf(e0.w, __low2float(v0), ax);  ay = fmaf(e0.w, __high2float(v0), ay);
        ax = fmaf(e1.w, __low2float(v1), ax);  ay = fmaf(e1.w, __high2float(v1), ay);
        ax = fmaf(e2.w, __low2float(v2), ax);  ay = fmaf(e2.w, __high2float(v2), ay);
        ax = fmaf(e3.w, __low2float(v3), ax);  ay = fmaf(e3.w, __high2float(v3), ay);
    }
    for (; j < end; ++j) {
        Edge e0 = edges[j];
        __hip_bfloat162 v0 = yv[(long long)e0.s * 64 + lane];
        ax = fmaf(e0.w, __low2float(v0), ax);
        ay = fmaf(e0.w, __high2float(v0), ay);
    }
    float2 bv = ((const float2*)b1)[lane];
    hs[wv][lane * 2]     = fmaxf(ax + bv.x, 0.f);
    hs[wv][lane * 2 + 1] = fmaxf(ay + bv.y, 0.f);
    __syncthreads();

    // gemm2 phase: wave wv computes node wv's 40 outputs; hs[wv][k] is a
    // same-address LDS broadcast (free), W2 reads coalesced over 40 lanes.
    if (lane < OUT_DIM) {
        const float4* h4 = (const float4*)hs[wv];
        float acc = 0.f;
        #pragma unroll
        for (int k4 = 0; k4 < HIDDEN / 4; ++k4) {
            float4 hv = h4[k4];
            acc = fmaf(hv.x, W2[(k4 * 4 + 0) * OUT_DIM + lane], acc);
            acc = fmaf(hv.y, W2[(k4 * 4 + 1) * OUT_DIM + lane], acc);
            acc = fmaf(hv.z, W2[(k4 * 4 + 2) * OUT_DIM + lane], acc);
            acc = fmaf(hv.w, W2[(k4 * 4 + 3) * OUT_DIM + lane], acc);
        }
        g[(long long)node * G_STRIDE + lane] = __float2bfloat16(acc);
    }
}

// ---- 5) spmm2: out = A @ g + b2; wave/node, 40 active lanes; g row is one
// aligned 128B line per edge gather ----------------------------------------
__global__ __launch_bounds__(256) void spmm2_kernel(const int* __restrict__ row_ptr,
                                                    const Edge* __restrict__ edges,
                                                    const __hip_bfloat16* __restrict__ g,
                                                    const float* __restrict__ b2,
                                                    float* __restrict__ out)
{
    int node = blockIdx.x * 4 + (threadIdx.x >> 6);
    int lane = threadIdx.x & 63;
    if (node >= N_NODES) return;
    if (lane >= OUT_DIM) return;
    int beg = row_ptr[node];
    int end = row_ptr[node + 1];
    float acc = 0.f;
    int j = beg;
    for (; j + 3 < end; j += 4) {
        Edge e0 = edges[j];
        Edge e1 = edges[j + 1];
        Edge e2 = edges[j + 2];
        Edge e3 = edges[j + 3];
        float v0 = __bfloat162float(g[(long long)e0.s * G_STRIDE + lane]);
        float v1 = __bfloat162float(g[(long long)e1.s * G_STRIDE + lane]);
        float v2 = __bfloat162float(g[(long long)e2.s * G_STRIDE + lane]);
        float v3 = __bfloat162float(g[(long long)e3.s * G_STRIDE + lane]);
        acc = fmaf(e0.w, v0, acc);
        acc = fmaf(e1.w, v1, acc);
        acc = fmaf(e2.w, v2, acc);
        acc = fmaf(e3.w, v3, acc);
    }
    for (; j < end; ++j) {
        Edge e0 = edges[j];
        acc = fmaf(e0.w, __bfloat162float(g[(long long)e0.s * G_STRIDE + lane]), acc);
    }
    out[(long long)node * OUT_DIM + lane] = acc + b2[lane];
}

extern "C" void kernel_launch(void* const* d_in, const int* in_sizes, int n_in,
                              void* d_out, int out_size, void* d_ws, size_t ws_size,
                              hipStream_t stream)
{
    const float* x    = (const float*)d_in[0];
    const int*   esrc = (const int*)  d_in[1];
    const int*   edst = (const int*)  d_in[2];
    const float* ew   = (const float*)d_in[3];
    const float* W1   = (const float*)d_in[4];
    const float* b1   = (const float*)d_in[5];
    const float* W2   = (const float*)d_in[6];
    const float* b2   = (const float*)d_in[7];
    float* out = (float*)d_out;

    // workspace layout (~35 MB)
    __hip_bfloat16* y  = (__hip_bfloat16*)d_ws;                  // 12.8 MB
    __hip_bfloat16* g  = y + (size_t)N_NODES * HIDDEN;           // 6.4 MB (padded rows)
    Edge* edges     = (Edge*)(g + (size_t)N_NODES * G_STRIDE);   // 6.4 MB
    int* hist8      = (int*)(edges + N_EDGES);                   // 1.6 MB
    int* erank      = hist8 + N_BUCKETS * HIST_STRIDE;           // 3.2 MB
    int* cnt        = erank + N_EDGES;                           // 200 KB
    int* row_ptr    = cnt + 50176;                               // 50001 (pad 50176)
    int* block_sums = row_ptr + 50176;                           // 64 ints

    // CSR build + gemm1 co-run: hist blocks and MFMA blocks in one dispatch
    hipMemsetAsync(hist8, 0, N_BUCKETS * HIST_STRIDE * sizeof(int), stream);
    hist_gemm1<<<HIST_BLOCKS + G1_BLOCKS, 256, 0, stream>>>(edst, hist8, erank,
                                                            x, W1, y);
    scan_partial<<<SCAN_BLOCKS, SCAN_BS, 0, stream>>>(hist8, cnt, block_sums);
    scan_final<<<SCAN_BLOCKS, SCAN_BS, 0, stream>>>(cnt, block_sums, row_ptr);
    scatter_det<<<SC_CHUNKS * N_BUCKETS, 256, 0, stream>>>(esrc, edst, ew, hist8,
                                                           erank, row_ptr, edges);

    // h1 = relu(A @ y + b1) in LDS; g = h1 @ W2 fused (padded rows)
    spmm1_gemm2<<<N_NODES / 4, 256, 0, stream>>>(row_ptr, edges, y, b1, W2, g);
    // out = A @ g + b2
    spmm2_kernel<<<(N_NODES + 3) / 4, 256, 0, stream>>>(row_ptr, edges, g, b2, out);
}

// Round 2
// 262.363 us; speedup vs baseline: 1.0417x; 1.0417x over previous
//
#include <hip/hip_runtime.h>
#include <hip/hip_bf16.h>

#define N_NODES 50000
#define N_EDGES 800000
#define IN_DIM 128
#define HIDDEN 128
#define OUT_DIM 40
#define G_STRIDE 64                                       // padded g row (128B line)

#define SCAN_BS 1024
#define SCAN_BLOCKS ((N_NODES + SCAN_BS - 1) / SCAN_BS)   // 49

#define N_BUCKETS 8
#define BUCKET_NODES (N_NODES / N_BUCKETS)                // 6250
#define HIST_STRIDE 50176                                 // line-aligned copy stride

#define SC_CHUNK 2048                                     // edges per scatter chunk
#define SC_CHUNKS ((N_EDGES + SC_CHUNK - 1) / SC_CHUNK)   // 391

#define HIST_BLOCKS (N_EDGES / 256)                       // 3125
#define G1_BLOCKS ((N_NODES + 63) / 64)                   // 782

struct __align__(8) Edge { int s; float w; };

typedef __attribute__((ext_vector_type(8))) short bf16x8;   // MFMA A/B frag (4 VGPR)
typedef __attribute__((ext_vector_type(4))) float f32x4;    // MFMA C/D frag

// fp32 -> bf16 bits with round-to-nearest-even
__device__ __forceinline__ unsigned f32_to_bf16_bits(float f) {
    unsigned u = __float_as_uint(f);
    return (u + 0x7FFFu + ((u >> 16) & 1u)) >> 16;
}

// ---- 1) fused hist + gemm1: hist blocks (0..3124) build the XCD-private
// ranked histogram; gemm1 blocks (3125..3906) compute y = x @ W1 via MFMA.
__global__ __launch_bounds__(256) void hist_gemm1(const int* __restrict__ dst,
                                                  int* __restrict__ hist8,
                                                  int* __restrict__ erank,
                                                  const float* __restrict__ x,
                                                  const float* __restrict__ W1,
                                                  __hip_bfloat16* __restrict__ y)
{
    __shared__ bf16x8 w1s[2048];                  // 32 KB (gemm1 blocks only)
    int bid = blockIdx.x;

    if (bid < HIST_BLOCKS) {
        // -------- hist path --------
        int i = bid * 256 + threadIdx.x;          // exact: 3125*256 = 800000
        int copy = bid & (N_BUCKETS - 1);
        erank[i] = atomicAdd(&hist8[copy * HIST_STRIDE + dst[i]], 1);
        return;
    }

    // -------- gemm1 path: y = x @ W1 (v_mfma_f32_16x16x32_bf16) --------
    int gb = bid - HIST_BLOCKS;
    int t = threadIdx.x;
    for (int f = t; f < 2048; f += 256) {         // 8 frags per thread
        int lane = f & 63;
        int nt = (f >> 6) & 7;
        int ks = f >> 9;
        int m = lane & 15, quad = lane >> 4;
        bf16x8 frag;
        #pragma unroll
        for (int j = 0; j < 8; ++j) {
            int k = ks * 32 + quad * 8 + j;
            frag[j] = (short)f32_to_bf16_bits(W1[k * HIDDEN + nt * 16 + m]);
        }
        w1s[f] = frag;
    }
    __syncthreads();

    int wv = t >> 6;
    int lane = t & 63;
    int m = lane & 15, quad = lane >> 4;
    int row0 = gb * 64 + wv * 16;
    int arow = row0 + m;
    if (arow >= N_NODES) arow = N_NODES - 1;      // clamp loads; stores guarded

    bf16x8 afrag[4];
    #pragma unroll
    for (int ks = 0; ks < 4; ++ks) {
        const float4* xp = (const float4*)(x + (long long)arow * IN_DIM + ks * 32 + quad * 8);
        float4 a0 = xp[0], a1 = xp[1];
        afrag[ks][0] = (short)f32_to_bf16_bits(a0.x);
        afrag[ks][1] = (short)f32_to_bf16_bits(a0.y);
        afrag[ks][2] = (short)f32_to_bf16_bits(a0.z);
        afrag[ks][3] = (short)f32_to_bf16_bits(a0.w);
        afrag[ks][4] = (short)f32_to_bf16_bits(a1.x);
        afrag[ks][5] = (short)f32_to_bf16_bits(a1.y);
        afrag[ks][6] = (short)f32_to_bf16_bits(a1.z);
        afrag[ks][7] = (short)f32_to_bf16_bits(a1.w);
    }

    f32x4 acc[8];
    #pragma unroll
    for (int nt = 0; nt < 8; ++nt) acc[nt] = (f32x4){0.f, 0.f, 0.f, 0.f};

    #pragma unroll
    for (int ks = 0; ks < 4; ++ks) {
        #pragma unroll
        for (int nt = 0; nt < 8; ++nt) {
            bf16x8 bfrag = w1s[(ks * 8 + nt) * 64 + lane];
            acc[nt] = __builtin_amdgcn_mfma_f32_16x16x32_bf16(afrag[ks], bfrag, acc[nt], 0, 0, 0);
        }
    }

    #pragma unroll
    for (int nt = 0; nt < 8; ++nt) {
        #pragma unroll
        for (int r = 0; r < 4; ++r) {
            int rrow = row0 + quad * 4 + r;
            if (rrow < N_NODES)
                y[(long long)rrow * HIDDEN + nt * 16 + m] = __float2bfloat16(acc[nt][r]);
        }
    }
}

// ---- 2a) convert 8 copies -> per-copy exclusive offsets (in place),
// total into cnt, plus per-block partial sums for the scan ----------------
__global__ __launch_bounds__(SCAN_BS) void scan_partial(int* __restrict__ hist8,
                                                        int* __restrict__ cnt,
                                                        int* __restrict__ block_sums)
{
    __shared__ int red[SCAN_BS / 64];
    int i = blockIdx.x * SCAN_BS + threadIdx.x;
    int total = 0;
    if (i < N_NODES) {
        int off = 0;
        #pragma unroll
        for (int c = 0; c < N_BUCKETS; ++c) {
            int h = hist8[c * HIST_STRIDE + i];
            hist8[c * HIST_STRIDE + i] = off;     // exclusive prefix over copies
            off += h;
        }
        total = off;
        cnt[i] = total;
    }
    int s = total;
    for (int off = 32; off > 0; off >>= 1) s += __shfl_down(s, off, 64);
    int wave = threadIdx.x >> 6, lane = threadIdx.x & 63;
    if (lane == 0) red[wave] = s;
    __syncthreads();
    if (threadIdx.x == 0) {
        int tt = 0;
        #pragma unroll
        for (int wv = 0; wv < SCAN_BS / 64; ++wv) tt += red[wv];
        block_sums[blockIdx.x] = tt;
    }
}

// ---- 2b) block-local exclusive scan; inline prefix over raw block_sums ----
__global__ __launch_bounds__(SCAN_BS) void scan_final(const int* __restrict__ cnt,
                                                      const int* __restrict__ block_sums,
                                                      int* __restrict__ row_ptr)
{
    __shared__ int tmp[SCAN_BS];
    __shared__ int blk_off;
    int t = threadIdx.x;
    int i = blockIdx.x * SCAN_BS + t;
    if (t == 0) {
        int s = 0;
        for (int j = 0; j < (int)blockIdx.x; ++j) s += block_sums[j];
        blk_off = s;
        if (blockIdx.x == 0) row_ptr[N_NODES] = N_EDGES;
    }
    int v = (i < N_NODES) ? cnt[i] : 0;
    tmp[t] = v;
    __syncthreads();
    for (int off = 1; off < SCAN_BS; off <<= 1) {
        int u = (t >= off) ? tmp[t - off] : 0;
        __syncthreads();
        tmp[t] += u;
        __syncthreads();
    }
    if (i < N_NODES) row_ptr[i] = tmp[t] - v + blk_off;
}

// ---- 3) scatter_det: deterministic bucket-filtered placement, NO atomics.
__global__ __launch_bounds__(256) void scatter_det(const int* __restrict__ src,
                                                   const int* __restrict__ dst,
                                                   const float* __restrict__ w,
                                                   const int* __restrict__ hist8,
                                                   const int* __restrict__ erank,
                                                   const int* __restrict__ row_ptr,
                                                   Edge* __restrict__ edges)
{
    int q     = blockIdx.x & (N_BUCKETS - 1);
    int chunk = blockIdx.x >> 3;                  // 0..390
    int base  = chunk * SC_CHUNK;
    int lo = q * BUCKET_NODES;
    int hi = lo + BUCKET_NODES;
    #pragma unroll
    for (int r = 0; r < SC_CHUNK / 256; ++r) {
        int i = base + r * 256 + threadIdx.x;
        if (i < N_EDGES) {
            int d = dst[i];
            if (d >= lo && d < hi) {
                int copy = (i >> 8) & (N_BUCKETS - 1);   // == hist's blockIdx&7
                int pos = row_ptr[d] + hist8[copy * HIST_STRIDE + d] + erank[i];
                Edge ed; ed.s = src[i]; ed.w = w[i];
                edges[pos] = ed;
            }
        }
    }
}

// ---- 4) fused spmm1 + gemm2: h1 = relu(A @ y + b1) stays in LDS (f32),
// g = h1 @ W2 computed by the SAME wave (no block barrier: producer wave ==
// consumer wave, a wave-local lgkmcnt(0) suffices). 8-deep gather unroll
// doubles outstanding L2/L3 misses per wave (latency-bound phase).
__global__ __launch_bounds__(256) void spmm1_gemm2(const int* __restrict__ row_ptr,
                                                   const Edge* __restrict__ edges,
                                                   const __hip_bfloat16* __restrict__ y,
                                                   const float* __restrict__ b1,
                                                   const float* __restrict__ W2,
                                                   __hip_bfloat16* __restrict__ g)
{
    __shared__ float hs[4][HIDDEN];               // 2 KB, f32
    int wv = threadIdx.x >> 6;
    int lane = threadIdx.x & 63;
    int node = blockIdx.x * 4 + wv;               // grid exact: 12500*4 = 50000
    int beg = row_ptr[node];
    int end = row_ptr[node + 1];
    const __hip_bfloat162* yv = (const __hip_bfloat162*)y;
    float ax = 0.f, ay = 0.f;
    int j = beg;
    for (; j + 7 < end; j += 8) {                 // 8 gathers in flight
        Edge e0 = edges[j + 0];
        Edge e1 = edges[j + 1];
        Edge e2 = edges[j + 2];
        Edge e3 = edges[j + 3];
        Edge e4 = edges[j + 4];
        Edge e5 = edges[j + 5];
        Edge e6 = edges[j + 6];
        Edge e7 = edges[j + 7];
        __hip_bfloat162 v0 = yv[(e0.s << 6) + lane];
        __hip_bfloat162 v1 = yv[(e1.s << 6) + lane];
        __hip_bfloat162 v2 = yv[(e2.s << 6) + lane];
        __hip_bfloat162 v3 = yv[(e3.s << 6) + lane];
        __hip_bfloat162 v4 = yv[(e4.s << 6) + lane];
        __hip_bfloat162 v5 = yv[(e5.s << 6) + lane];
        __hip_bfloat162 v6 = yv[(e6.s << 6) + lane];
        __hip_bfloat162 v7 = yv[(e7.s << 6) + lane];
        ax = fmaf(e0.w, __low2float(v0), ax);  ay = fmaf(e0.w, __high2float(v0), ay);
        ax = fmaf(e1.w, __low2float(v1), ax);  ay = fmaf(e1.w, __high2float(v1), ay);
        ax = fmaf(e2.w, __low2float(v2), ax);  ay = fmaf(e2.w, __high2float(v2), ay);
        ax = fmaf(e3.w, __low2float(v3), ax);  ay = fmaf(e3.w, __high2float(v3), ay);
        ax = fmaf(e4.w, __low2float(v4), ax);  ay = fmaf(e4.w, __high2float(v4), ay);
        ax = fmaf(e5.w, __low2float(v5), ax);  ay = fmaf(e5.w, __high2float(v5), ay);
        ax = fmaf(e6.w, __low2float(v6), ax);  ay = fmaf(e6.w, __high2float(v6), ay);
        ax = fmaf(e7.w, __low2float(v7), ax);  ay = fmaf(e7.w, __high2float(v7), ay);
    }
    for (; j + 3 < end; j += 4) {
        Edge e0 = edges[j + 0];
        Edge e1 = edges[j + 1];
        Edge e2 = edges[j + 2];
        Edge e3 = edges[j + 3];
        __hip_bfloat162 v0 = yv[(e0.s << 6) + lane];
        __hip_bfloat162 v1 = yv[(e1.s << 6) + lane];
        __hip_bfloat162 v2 = yv[(e2.s << 6) + lane];
        __hip_bfloat162 v3 = yv[(e3.s << 6) + lane];
        ax = fmaf(e0.w, __low2float(v0), ax);  ay = fmaf(e0.w, __high2float(v0), ay);
        ax = fmaf(e1.w, __low2float(v1), ax);  ay = fmaf(e1.w, __high2float(v1), ay);
        ax = fmaf(e2.w, __low2float(v2), ax);  ay = fmaf(e2.w, __high2float(v2), ay);
        ax = fmaf(e3.w, __low2float(v3), ax);  ay = fmaf(e3.w, __high2float(v3), ay);
    }
    for (; j < end; ++j) {
        Edge e0 = edges[j];
        __hip_bfloat162 v0 = yv[(e0.s << 6) + lane];
        ax = fmaf(e0.w, __low2float(v0), ax);
        ay = fmaf(e0.w, __high2float(v0), ay);
    }
    float2 bv = ((const float2*)b1)[lane];
    hs[wv][lane * 2]     = fmaxf(ax + bv.x, 0.f);
    hs[wv][lane * 2 + 1] = fmaxf(ay + bv.y, 0.f);
    // wave-local LDS handoff: drain this wave's ds_writes; no block barrier
    asm volatile("s_waitcnt lgkmcnt(0)" ::: "memory");

    // gemm2 phase: wave wv computes node wv's 40 outputs from hs[wv]
    // (same-address LDS broadcast), W2 reads coalesced over 40 lanes.
    if (lane < OUT_DIM) {
        const float4* h4 = (const float4*)hs[wv];
        float acc = 0.f;
        #pragma unroll
        for (int k4 = 0; k4 < HIDDEN / 4; ++k4) {
            float4 hv = h4[k4];
            acc = fmaf(hv.x, W2[(k4 * 4 + 0) * OUT_DIM + lane], acc);
            acc = fmaf(hv.y, W2[(k4 * 4 + 1) * OUT_DIM + lane], acc);
            acc = fmaf(hv.z, W2[(k4 * 4 + 2) * OUT_DIM + lane], acc);
            acc = fmaf(hv.w, W2[(k4 * 4 + 3) * OUT_DIM + lane], acc);
        }
        g[(node << 6) + lane] = __float2bfloat16(acc);
    }
}

// ---- 5) spmm2: out = A @ g + b2; wave/node, 40 active lanes; g row is one
// aligned 128B line per edge gather; 8-deep gather unroll ------------------
__global__ __launch_bounds__(256) void spmm2_kernel(const int* __restrict__ row_ptr,
                                                    const Edge* __restrict__ edges,
                                                    const __hip_bfloat16* __restrict__ g,
                                                    const float* __restrict__ b2,
                                                    float* __restrict__ out)
{
    int node = blockIdx.x * 4 + (threadIdx.x >> 6);
    int lane = threadIdx.x & 63;
    if (node >= N_NODES) return;
    if (lane >= OUT_DIM) return;
    int beg = row_ptr[node];
    int end = row_ptr[node + 1];
    float acc = 0.f;
    int j = beg;
    for (; j + 7 < end; j += 8) {
        Edge e0 = edges[j + 0];
        Edge e1 = edges[j + 1];
        Edge e2 = edges[j + 2];
        Edge e3 = edges[j + 3];
        Edge e4 = edges[j + 4];
        Edge e5 = edges[j + 5];
        Edge e6 = edges[j + 6];
        Edge e7 = edges[j + 7];
        float v0 = __bfloat162float(g[(e0.s << 6) + lane]);
        float v1 = __bfloat162float(g[(e1.s << 6) + lane]);
        float v2 = __bfloat162float(g[(e2.s << 6) + lane]);
        float v3 = __bfloat162float(g[(e3.s << 6) + lane]);
        float v4 = __bfloat162float(g[(e4.s << 6) + lane]);
        float v5 = __bfloat162float(g[(e5.s << 6) + lane]);
        float v6 = __bfloat162float(g[(e6.s << 6) + lane]);
        float v7 = __bfloat162float(g[(e7.s << 6) + lane]);
        acc = fmaf(e0.w, v0, acc);
        acc = fmaf(e1.w, v1, acc);
        acc = fmaf(e2.w, v2, acc);
        acc = fmaf(e3.w, v3, acc);
        acc = fmaf(e4.w, v4, acc);
        acc = fmaf(e5.w, v5, acc);
        acc = fmaf(e6.w, v6, acc);
        acc = fmaf(e7.w, v7, acc);
    }
    for (; j + 3 < end; j += 4) {
        Edge e0 = edges[j + 0];
        Edge e1 = edges[j + 1];
        Edge e2 = edges[j + 2];
        Edge e3 = edges[j + 3];
        float v0 = __bfloat162float(g[(e0.s << 6) + lane]);
        float v1 = __bfloat162float(g[(e1.s << 6) + lane]);
        float v2 = __bfloat162float(g[(e2.s << 6) + lane]);
        float v3 = __bfloat162float(g[(e3.s << 6) + lane]);
        acc = fmaf(e0.w, v0, acc);
        acc = fmaf(e1.w, v1, acc);
        acc = fmaf(e2.w, v2, acc);
        acc = fmaf(e3.w, v3, acc);
    }
    for (; j < end; ++j) {
        Edge e0 = edges[j];
        acc = fmaf(e0.w, __bfloat162float(g[(e0.s << 6) + lane]), acc);
    }
    out[(long long)node * OUT_DIM + lane] = acc + b2[lane];
}

extern "C" void kernel_launch(void* const* d_in, const int* in_sizes, int n_in,
                              void* d_out, int out_size, void* d_ws, size_t ws_size,
                              hipStream_t stream)
{
    const float* x    = (const float*)d_in[0];
    const int*   esrc = (const int*)  d_in[1];
    const int*   edst = (const int*)  d_in[2];
    const float* ew   = (const float*)d_in[3];
    const float* W1   = (const float*)d_in[4];
    const float* b1   = (const float*)d_in[5];
    const float* W2   = (const float*)d_in[6];
    const float* b2   = (const float*)d_in[7];
    float* out = (float*)d_out;

    // workspace layout (~35 MB)
    __hip_bfloat16* y  = (__hip_bfloat16*)d_ws;                  // 12.8 MB
    __hip_bfloat16* g  = y + (size_t)N_NODES * HIDDEN;           // 6.4 MB (padded rows)
    Edge* edges     = (Edge*)(g + (size_t)N_NODES * G_STRIDE);   // 6.4 MB
    int* hist8      = (int*)(edges + N_EDGES);                   // 1.6 MB
    int* erank      = hist8 + N_BUCKETS * HIST_STRIDE;           // 3.2 MB
    int* cnt        = erank + N_EDGES;                           // 200 KB
    int* row_ptr    = cnt + 50176;                               // 50001 (pad 50176)
    int* block_sums = row_ptr + 50176;                           // 64 ints

    // CSR build + gemm1 co-run: hist blocks and MFMA blocks in one dispatch
    hipMemsetAsync(hist8, 0, N_BUCKETS * HIST_STRIDE * sizeof(int), stream);
    hist_gemm1<<<HIST_BLOCKS + G1_BLOCKS, 256, 0, stream>>>(edst, hist8, erank,
                                                            x, W1, y);
    scan_partial<<<SCAN_BLOCKS, SCAN_BS, 0, stream>>>(hist8, cnt, block_sums);
    scan_final<<<SCAN_BLOCKS, SCAN_BS, 0, stream>>>(cnt, block_sums, row_ptr);
    scatter_det<<<SC_CHUNKS * N_BUCKETS, 256, 0, stream>>>(esrc, edst, ew, hist8,
                                                           erank, row_ptr, edges);

    // h1 = relu(A @ y + b1) in LDS; g = h1 @ W2 fused (no block barrier)
    spmm1_gemm2<<<N_NODES / 4, 256, 0, stream>>>(row_ptr, edges, y, b1, W2, g);
    // out = A @ g + b2
    spmm2_kernel<<<(N_NODES + 3) / 4, 256, 0, stream>>>(row_ptr, edges, g, b2, out);
}

// Round 3
// 246.181 us; speedup vs baseline: 1.1101x; 1.0657x over previous
//
#include <hip/hip_runtime.h>
#include <hip/hip_bf16.h>

#define N_NODES 50000
#define N_EDGES 800000
#define IN_DIM 128
#define HIDDEN 128
#define OUT_DIM 40
#define G_STRIDE 64                                       // padded g row (128B line)

#define SCAN_BS 1024
#define SCAN_BLOCKS ((N_NODES + SCAN_BS - 1) / SCAN_BS)   // 49

#define N_BUCKETS 8
#define BUCKET_NODES (N_NODES / N_BUCKETS)                // 6250
#define HIST_STRIDE 50176                                 // line-aligned copy stride

#define SC_CHUNK 2048                                     // edges per scatter chunk
#define SC_CHUNKS ((N_EDGES + SC_CHUNK - 1) / SC_CHUNK)   // 391

#define HIST_BLOCKS (N_EDGES / 256)                       // 3125
#define G1_BLOCKS ((N_NODES + 63) / 64)                   // 782

struct __align__(8) Edge { int s; float w; };

typedef __attribute__((ext_vector_type(8))) short bf16x8;   // MFMA A/B frag (4 VGPR)
typedef __attribute__((ext_vector_type(4))) float f32x4;    // MFMA C/D frag

// fp32 -> bf16 bits with round-to-nearest-even
__device__ __forceinline__ unsigned f32_to_bf16_bits(float f) {
    unsigned u = __float_as_uint(f);
    return (u + 0x7FFFu + ((u >> 16) & 1u)) >> 16;
}

// ---- 1) fused hist + gemm1: hist blocks (0..3124) build the XCD-private
// ranked histogram; gemm1 blocks (3125..3906) compute y = x @ W1 via MFMA.
// Independent work co-runs in one dispatch.
__global__ __launch_bounds__(256) void hist_gemm1(const int* __restrict__ dst,
                                                  int* __restrict__ hist8,
                                                  int* __restrict__ erank,
                                                  const float* __restrict__ x,
                                                  const float* __restrict__ W1,
                                                  __hip_bfloat16* __restrict__ y)
{
    __shared__ bf16x8 w1s[2048];                  // 32 KB (gemm1 blocks only)
    int bid = blockIdx.x;

    if (bid < HIST_BLOCKS) {
        // -------- hist path --------
        int i = bid * 256 + threadIdx.x;          // exact: 3125*256 = 800000
        int copy = bid & (N_BUCKETS - 1);
        erank[i] = atomicAdd(&hist8[copy * HIST_STRIDE + dst[i]], 1);
        return;
    }

    // -------- gemm1 path: y = x @ W1 (v_mfma_f32_16x16x32_bf16) --------
    int gb = bid - HIST_BLOCKS;
    int t = threadIdx.x;
    for (int f = t; f < 2048; f += 256) {         // 8 frags per thread
        int lane = f & 63;
        int nt = (f >> 6) & 7;
        int ks = f >> 9;
        int m = lane & 15, quad = lane >> 4;
        bf16x8 frag;
        #pragma unroll
        for (int j = 0; j < 8; ++j) {
            int k = ks * 32 + quad * 8 + j;
            frag[j] = (short)f32_to_bf16_bits(W1[k * HIDDEN + nt * 16 + m]);
        }
        w1s[f] = frag;
    }
    __syncthreads();

    int wv = t >> 6;
    int lane = t & 63;
    int m = lane & 15, quad = lane >> 4;
    int row0 = gb * 64 + wv * 16;
    int arow = row0 + m;
    if (arow >= N_NODES) arow = N_NODES - 1;      // clamp loads; stores guarded

    bf16x8 afrag[4];
    #pragma unroll
    for (int ks = 0; ks < 4; ++ks) {
        const float4* xp = (const float4*)(x + (long long)arow * IN_DIM + ks * 32 + quad * 8);
        float4 a0 = xp[0], a1 = xp[1];
        afrag[ks][0] = (short)f32_to_bf16_bits(a0.x);
        afrag[ks][1] = (short)f32_to_bf16_bits(a0.y);
        afrag[ks][2] = (short)f32_to_bf16_bits(a0.z);
        afrag[ks][3] = (short)f32_to_bf16_bits(a0.w);
        afrag[ks][4] = (short)f32_to_bf16_bits(a1.x);
        afrag[ks][5] = (short)f32_to_bf16_bits(a1.y);
        afrag[ks][6] = (short)f32_to_bf16_bits(a1.z);
        afrag[ks][7] = (short)f32_to_bf16_bits(a1.w);
    }

    f32x4 acc[8];
    #pragma unroll
    for (int nt = 0; nt < 8; ++nt) acc[nt] = (f32x4){0.f, 0.f, 0.f, 0.f};

    #pragma unroll
    for (int ks = 0; ks < 4; ++ks) {
        #pragma unroll
        for (int nt = 0; nt < 8; ++nt) {
            bf16x8 bfrag = w1s[(ks * 8 + nt) * 64 + lane];
            acc[nt] = __builtin_amdgcn_mfma_f32_16x16x32_bf16(afrag[ks], bfrag, acc[nt], 0, 0, 0);
        }
    }

    #pragma unroll
    for (int nt = 0; nt < 8; ++nt) {
        #pragma unroll
        for (int r = 0; r < 4; ++r) {
            int rrow = row0 + quad * 4 + r;
            if (rrow < N_NODES)
                y[(long long)rrow * HIDDEN + nt * 16 + m] = __float2bfloat16(acc[nt][r]);
        }
    }
}

// ---- 2a) convert 8 copies -> per-copy exclusive offsets (in place),
// total into cnt, plus per-block partial sums for the scan ----------------
__global__ __launch_bounds__(SCAN_BS) void scan_partial(int* __restrict__ hist8,
                                                        int* __restrict__ cnt,
                                                        int* __restrict__ block_sums)
{
    __shared__ int red[SCAN_BS / 64];
    int i = blockIdx.x * SCAN_BS + threadIdx.x;
    int total = 0;
    if (i < N_NODES) {
        int off = 0;
        #pragma unroll
        for (int c = 0; c < N_BUCKETS; ++c) {
            int h = hist8[c * HIST_STRIDE + i];
            hist8[c * HIST_STRIDE + i] = off;     // exclusive prefix over copies
            off += h;
        }
        total = off;
        cnt[i] = total;
    }
    int s = total;
    for (int off = 32; off > 0; off >>= 1) s += __shfl_down(s, off, 64);
    int wave = threadIdx.x >> 6, lane = threadIdx.x & 63;
    if (lane == 0) red[wave] = s;
    __syncthreads();
    if (threadIdx.x == 0) {
        int tt = 0;
        #pragma unroll
        for (int wv = 0; wv < SCAN_BS / 64; ++wv) tt += red[wv];
        block_sums[blockIdx.x] = tt;
    }
}

// ---- 2b) block-local exclusive scan; inline prefix over raw block_sums ----
__global__ __launch_bounds__(SCAN_BS) void scan_final(const int* __restrict__ cnt,
                                                      const int* __restrict__ block_sums,
                                                      int* __restrict__ row_ptr)
{
    __shared__ int tmp[SCAN_BS];
    __shared__ int blk_off;
    int t = threadIdx.x;
    int i = blockIdx.x * SCAN_BS + t;
    if (t == 0) {
        int s = 0;
        for (int j = 0; j < (int)blockIdx.x; ++j) s += block_sums[j];
        blk_off = s;
        if (blockIdx.x == 0) row_ptr[N_NODES] = N_EDGES;
    }
    int v = (i < N_NODES) ? cnt[i] : 0;
    tmp[t] = v;
    __syncthreads();
    for (int off = 1; off < SCAN_BS; off <<= 1) {
        int u = (t >= off) ? tmp[t - off] : 0;
        __syncthreads();
        tmp[t] += u;
        __syncthreads();
    }
    if (i < N_NODES) row_ptr[i] = tmp[t] - v + blk_off;
}

// ---- 3) scatter_det: deterministic bucket-filtered placement, NO atomics.
__global__ __launch_bounds__(256) void scatter_det(const int* __restrict__ src,
                                                   const int* __restrict__ dst,
                                                   const float* __restrict__ w,
                                                   const int* __restrict__ hist8,
                                                   const int* __restrict__ erank,
                                                   const int* __restrict__ row_ptr,
                                                   Edge* __restrict__ edges)
{
    int q     = blockIdx.x & (N_BUCKETS - 1);
    int chunk = blockIdx.x >> 3;                  // 0..390
    int base  = chunk * SC_CHUNK;
    int lo = q * BUCKET_NODES;
    int hi = lo + BUCKET_NODES;
    #pragma unroll
    for (int r = 0; r < SC_CHUNK / 256; ++r) {
        int i = base + r * 256 + threadIdx.x;
        if (i < N_EDGES) {
            int d = dst[i];
            if (d >= lo && d < hi) {
                int copy = (i >> 8) & (N_BUCKETS - 1);   // == hist's blockIdx&7
                int pos = row_ptr[d] + hist8[copy * HIST_STRIDE + d] + erank[i];
                Edge ed; ed.s = src[i]; ed.w = w[i];
                edges[pos] = ed;
            }
        }
    }
}

// ---- 4) spmm1: h1 = relu(A @ y + b1); wave/node, 8-deep gather unroll -----
__global__ __launch_bounds__(256) void spmm1_kernel(const int* __restrict__ row_ptr,
                                                    const Edge* __restrict__ edges,
                                                    const __hip_bfloat16* __restrict__ y,
                                                    const float* __restrict__ b1,
                                                    __hip_bfloat16* __restrict__ h1)
{
    int node = blockIdx.x * 4 + (threadIdx.x >> 6);
    int lane = threadIdx.x & 63;
    if (node >= N_NODES) return;
    int beg = row_ptr[node];
    int end = row_ptr[node + 1];
    const __hip_bfloat162* yv = (const __hip_bfloat162*)y;
    float ax = 0.f, ay = 0.f;
    int j = beg;
    for (; j + 7 < end; j += 8) {                 // 8 gathers in flight
        Edge e0 = edges[j + 0];
        Edge e1 = edges[j + 1];
        Edge e2 = edges[j + 2];
        Edge e3 = edges[j + 3];
        Edge e4 = edges[j + 4];
        Edge e5 = edges[j + 5];
        Edge e6 = edges[j + 6];
        Edge e7 = edges[j + 7];
        __hip_bfloat162 v0 = yv[(e0.s << 6) + lane];
        __hip_bfloat162 v1 = yv[(e1.s << 6) + lane];
        __hip_bfloat162 v2 = yv[(e2.s << 6) + lane];
        __hip_bfloat162 v3 = yv[(e3.s << 6) + lane];
        __hip_bfloat162 v4 = yv[(e4.s << 6) + lane];
        __hip_bfloat162 v5 = yv[(e5.s << 6) + lane];
        __hip_bfloat162 v6 = yv[(e6.s << 6) + lane];
        __hip_bfloat162 v7 = yv[(e7.s << 6) + lane];
        ax = fmaf(e0.w, __low2float(v0), ax);  ay = fmaf(e0.w, __high2float(v0), ay);
        ax = fmaf(e1.w, __low2float(v1), ax);  ay = fmaf(e1.w, __high2float(v1), ay);
        ax = fmaf(e2.w, __low2float(v2), ax);  ay = fmaf(e2.w, __high2float(v2), ay);
        ax = fmaf(e3.w, __low2float(v3), ax);  ay = fmaf(e3.w, __high2float(v3), ay);
        ax = fmaf(e4.w, __low2float(v4), ax);  ay = fmaf(e4.w, __high2float(v4), ay);
        ax = fmaf(e5.w, __low2float(v5), ax);  ay = fmaf(e5.w, __high2float(v5), ay);
        ax = fmaf(e6.w, __low2float(v6), ax);  ay = fmaf(e6.w, __high2float(v6), ay);
        ax = fmaf(e7.w, __low2float(v7), ax);  ay = fmaf(e7.w, __high2float(v7), ay);
    }
    for (; j + 3 < end; j += 4) {
        Edge e0 = edges[j + 0];
        Edge e1 = edges[j + 1];
        Edge e2 = edges[j + 2];
        Edge e3 = edges[j + 3];
        __hip_bfloat162 v0 = yv[(e0.s << 6) + lane];
        __hip_bfloat162 v1 = yv[(e1.s << 6) + lane];
        __hip_bfloat162 v2 = yv[(e2.s << 6) + lane];
        __hip_bfloat162 v3 = yv[(e3.s << 6) + lane];
        ax = fmaf(e0.w, __low2float(v0), ax);  ay = fmaf(e0.w, __high2float(v0), ay);
        ax = fmaf(e1.w, __low2float(v1), ax);  ay = fmaf(e1.w, __high2float(v1), ay);
        ax = fmaf(e2.w, __low2float(v2), ax);  ay = fmaf(e2.w, __high2float(v2), ay);
        ax = fmaf(e3.w, __low2float(v3), ax);  ay = fmaf(e3.w, __high2float(v3), ay);
    }
    for (; j < end; ++j) {
        Edge e0 = edges[j];
        __hip_bfloat162 v0 = yv[(e0.s << 6) + lane];
        ax = fmaf(e0.w, __low2float(v0), ax);
        ay = fmaf(e0.w, __high2float(v0), ay);
    }
    float2 bv = ((const float2*)b1)[lane];
    __hip_bfloat162 hv;
    hv.x = __float2bfloat16(fmaxf(ax + bv.x, 0.f));
    hv.y = __float2bfloat16(fmaxf(ay + bv.y, 0.f));
    ((__hip_bfloat162*)h1)[(node << 6) + lane] = hv;
}

// ---- 5) gemm2: g = h1 @ W2; 8 rows/block amortize the W2 pass (128 scalar
// W2 loads serve 8 nodes -> 800K total W2 load instrs, not 6.4M) -----------
#define G2_ROWS 8
__global__ __launch_bounds__(64) void gemm2_kernel(const __hip_bfloat16* __restrict__ h1,
                                                   const float* __restrict__ W2,
                                                   __hip_bfloat16* __restrict__ g)
{
    __shared__ float xs[G2_ROWS][HIDDEN];
    int row0 = blockIdx.x * G2_ROWS;
    int t = threadIdx.x;
    #pragma unroll
    for (int r = 0; r < G2_ROWS; ++r) {
        xs[r][t]      = __bfloat162float(h1[(long long)(row0 + r) * HIDDEN + t]);
        xs[r][t + 64] = __bfloat162float(h1[(long long)(row0 + r) * HIDDEN + t + 64]);
    }
    __syncthreads();
    if (t >= OUT_DIM) return;
    float acc[G2_ROWS];
    #pragma unroll
    for (int r = 0; r < G2_ROWS; ++r) acc[r] = 0.f;
    #pragma unroll 4
    for (int k = 0; k < HIDDEN; ++k) {
        float wv = W2[k * OUT_DIM + t];
        #pragma unroll
        for (int r = 0; r < G2_ROWS; ++r)
            acc[r] = fmaf(xs[r][k], wv, acc[r]);
    }
    #pragma unroll
    for (int r = 0; r < G2_ROWS; ++r)
        g[((row0 + r) << 6) + t] = __float2bfloat16(acc[r]);   // padded row
}

// ---- 6) spmm2: out = A @ g + b2; wave/node, 40 active lanes; g row is one
// aligned 128B line per edge gather; 8-deep gather unroll ------------------
__global__ __launch_bounds__(256) void spmm2_kernel(const int* __restrict__ row_ptr,
                                                    const Edge* __restrict__ edges,
                                                    const __hip_bfloat16* __restrict__ g,
                                                    const float* __restrict__ b2,
                                                    float* __restrict__ out)
{
    int node = blockIdx.x * 4 + (threadIdx.x >> 6);
    int lane = threadIdx.x & 63;
    if (node >= N_NODES) return;
    if (lane >= OUT_DIM) return;
    int beg = row_ptr[node];
    int end = row_ptr[node + 1];
    float acc = 0.f;
    int j = beg;
    for (; j + 7 < end; j += 8) {
        Edge e0 = edges[j + 0];
        Edge e1 = edges[j + 1];
        Edge e2 = edges[j + 2];
        Edge e3 = edges[j + 3];
        Edge e4 = edges[j + 4];
        Edge e5 = edges[j + 5];
        Edge e6 = edges[j + 6];
        Edge e7 = edges[j + 7];
        float v0 = __bfloat162float(g[(e0.s << 6) + lane]);
        float v1 = __bfloat162float(g[(e1.s << 6) + lane]);
        float v2 = __bfloat162float(g[(e2.s << 6) + lane]);
        float v3 = __bfloat162float(g[(e3.s << 6) + lane]);
        float v4 = __bfloat162float(g[(e4.s << 6) + lane]);
        float v5 = __bfloat162float(g[(e5.s << 6) + lane]);
        float v6 = __bfloat162float(g[(e6.s << 6) + lane]);
        float v7 = __bfloat162float(g[(e7.s << 6) + lane]);
        acc = fmaf(e0.w, v0, acc);
        acc = fmaf(e1.w, v1, acc);
        acc = fmaf(e2.w, v2, acc);
        acc = fmaf(e3.w, v3, acc);
        acc = fmaf(e4.w, v4, acc);
        acc = fmaf(e5.w, v5, acc);
        acc = fmaf(e6.w, v6, acc);
        acc = fmaf(e7.w, v7, acc);
    }
    for (; j + 3 < end; j += 4) {
        Edge e0 = edges[j + 0];
        Edge e1 = edges[j + 1];
        Edge e2 = edges[j + 2];
        Edge e3 = edges[j + 3];
        float v0 = __bfloat162float(g[(e0.s << 6) + lane]);
        float v1 = __bfloat162float(g[(e1.s << 6) + lane]);
        float v2 = __bfloat162float(g[(e2.s << 6) + lane]);
        float v3 = __bfloat162float(g[(e3.s << 6) + lane]);
        acc = fmaf(e0.w, v0, acc);
        acc = fmaf(e1.w, v1, acc);
        acc = fmaf(e2.w, v2, acc);
        acc = fmaf(e3.w, v3, acc);
    }
    for (; j < end; ++j) {
        Edge e0 = edges[j];
        acc = fmaf(e0.w, __bfloat162float(g[(e0.s << 6) + lane]), acc);
    }
    out[(long long)node * OUT_DIM + lane] = acc + b2[lane];
}

extern "C" void kernel_launch(void* const* d_in, const int* in_sizes, int n_in,
                              void* d_out, int out_size, void* d_ws, size_t ws_size,
                              hipStream_t stream)
{
    const float* x    = (const float*)d_in[0];
    const int*   esrc = (const int*)  d_in[1];
    const int*   edst = (const int*)  d_in[2];
    const float* ew   = (const float*)d_in[3];
    const float* W1   = (const float*)d_in[4];
    const float* b1   = (const float*)d_in[5];
    const float* W2   = (const float*)d_in[6];
    const float* b2   = (const float*)d_in[7];
    float* out = (float*)d_out;

    // workspace layout (~38 MB); g aliases y (y is dead after spmm1)
    __hip_bfloat16* y  = (__hip_bfloat16*)d_ws;                  // 12.8 MB
    __hip_bfloat16* g  = y;                                      // 6.4 MB (aliased)
    __hip_bfloat16* h1 = y + (size_t)N_NODES * HIDDEN;           // 12.8 MB
    Edge* edges     = (Edge*)(h1 + (size_t)N_NODES * HIDDEN);    // 6.4 MB
    int* hist8      = (int*)(edges + N_EDGES);                   // 1.6 MB
    int* erank      = hist8 + N_BUCKETS * HIST_STRIDE;           // 3.2 MB
    int* cnt        = erank + N_EDGES;                           // 200 KB
    int* row_ptr    = cnt + 50176;                               // 50001 (pad 50176)
    int* block_sums = row_ptr + 50176;                           // 64 ints

    // CSR build + gemm1 co-run: hist blocks and MFMA blocks in one dispatch
    hipMemsetAsync(hist8, 0, N_BUCKETS * HIST_STRIDE * sizeof(int), stream);
    hist_gemm1<<<HIST_BLOCKS + G1_BLOCKS, 256, 0, stream>>>(edst, hist8, erank,
                                                            x, W1, y);
    scan_partial<<<SCAN_BLOCKS, SCAN_BS, 0, stream>>>(hist8, cnt, block_sums);
    scan_final<<<SCAN_BLOCKS, SCAN_BS, 0, stream>>>(cnt, block_sums, row_ptr);
    scatter_det<<<SC_CHUNKS * N_BUCKETS, 256, 0, stream>>>(esrc, edst, ew, hist8,
                                                           erank, row_ptr, edges);

    // h1 = relu(A @ y + b1)
    spmm1_kernel<<<N_NODES / 4, 256, 0, stream>>>(row_ptr, edges, y, b1, h1);
    // g = h1 @ W2 (8-row W2 amortization; padded g rows)
    gemm2_kernel<<<N_NODES / G2_ROWS, 64, 0, stream>>>(h1, W2, g);
    // out = A @ g + b2
    spmm2_kernel<<<(N_NODES + 3) / 4, 256, 0, stream>>>(row_ptr, edges, g, b2, out);
}

// Round 4
// 230.351 us; speedup vs baseline: 1.1864x; 1.0687x over previous
//
#include <hip/hip_runtime.h>
#include <hip/hip_bf16.h>

#define N_NODES 50000
#define N_EDGES 800000
#define IN_DIM 128
#define HIDDEN 128
#define OUT_DIM 40
#define G_STRIDE 64                                       // padded g row (128B line)

#define SCAN_BS 1024
#define SCAN_BLOCKS ((N_NODES + SCAN_BS - 1) / SCAN_BS)   // 49

#define N_BUCKETS 8
#define HIST_STRIDE 50176                                 // line-aligned copy stride

#define HIST_BLOCKS 3128                                  // covers 800768 slots (guarded)
#define G1_BLOCKS ((N_NODES + 63) / 64)                   // 782
#define HG_GRID 3910                                      // 782 gemm1 (bid%5==4) + 3128 hist

struct __align__(8) Edge { int s; float w; };

typedef __attribute__((ext_vector_type(8))) short bf16x8;   // MFMA A/B frag (4 VGPR)
typedef __attribute__((ext_vector_type(4))) float f32x4;    // MFMA C/D frag

// fp32 -> bf16 bits with round-to-nearest-even
__device__ __forceinline__ unsigned f32_to_bf16_bits(float f) {
    unsigned u = __float_as_uint(f);
    return (u + 0x7FFFu + ((u >> 16) & 1u)) >> 16;
}

// ---- 1) fused hist + gemm1, INTERLEAVED: every 5th block (bid%5==4) is a
// gemm1 MFMA block, the rest are hist blocks. Blocks dispatch ~in order, so
// interleaving keeps MFMA work resident during the whole atomic-bound hist
// phase (true overlap) instead of running as a serial tail.
__global__ __launch_bounds__(256) void hist_gemm1(const int* __restrict__ dst,
                                                  int* __restrict__ hist8,
                                                  int* __restrict__ erank,
                                                  const float* __restrict__ x,
                                                  const float* __restrict__ W1,
                                                  __hip_bfloat16* __restrict__ y)
{
    __shared__ bf16x8 w1s[2048];                  // 32 KB (gemm1 blocks only)
    int bid = blockIdx.x;

    if ((bid % 5) != 4) {
        // -------- hist path: hb = bid minus #gemm1-blocks-before-bid --------
        int hb = bid - bid / 5;                   // 0..3127
        int i = hb * 256 + threadIdx.x;
        if (i < N_EDGES) {
            int copy = hb & (N_BUCKETS - 1);      // == (i >> 8) & 7
            erank[i] = atomicAdd(&hist8[copy * HIST_STRIDE + dst[i]], 1);
        }
        return;
    }

    // -------- gemm1 path: y = x @ W1 (v_mfma_f32_16x16x32_bf16) --------
    int gb = bid / 5;                             // 0..781
    int t = threadIdx.x;
    for (int f = t; f < 2048; f += 256) {         // 8 frags per thread
        int lane = f & 63;
        int nt = (f >> 6) & 7;
        int ks = f >> 9;
        int m = lane & 15, quad = lane >> 4;
        bf16x8 frag;
        #pragma unroll
        for (int j = 0; j < 8; ++j) {
            int k = ks * 32 + quad * 8 + j;
            frag[j] = (short)f32_to_bf16_bits(W1[k * HIDDEN + nt * 16 + m]);
        }
        w1s[f] = frag;
    }
    __syncthreads();

    int wv = t >> 6;
    int lane = t & 63;
    int m = lane & 15, quad = lane >> 4;
    int row0 = gb * 64 + wv * 16;
    int arow = row0 + m;
    if (arow >= N_NODES) arow = N_NODES - 1;      // clamp loads; stores guarded

    bf16x8 afrag[4];
    #pragma unroll
    for (int ks = 0; ks < 4; ++ks) {
        const float4* xp = (const float4*)(x + (long long)arow * IN_DIM + ks * 32 + quad * 8);
        float4 a0 = xp[0], a1 = xp[1];
        afrag[ks][0] = (short)f32_to_bf16_bits(a0.x);
        afrag[ks][1] = (short)f32_to_bf16_bits(a0.y);
        afrag[ks][2] = (short)f32_to_bf16_bits(a0.z);
        afrag[ks][3] = (short)f32_to_bf16_bits(a0.w);
        afrag[ks][4] = (short)f32_to_bf16_bits(a1.x);
        afrag[ks][5] = (short)f32_to_bf16_bits(a1.y);
        afrag[ks][6] = (short)f32_to_bf16_bits(a1.z);
        afrag[ks][7] = (short)f32_to_bf16_bits(a1.w);
    }

    f32x4 acc[8];
    #pragma unroll
    for (int nt = 0; nt < 8; ++nt) acc[nt] = (f32x4){0.f, 0.f, 0.f, 0.f};

    #pragma unroll
    for (int ks = 0; ks < 4; ++ks) {
        #pragma unroll
        for (int nt = 0; nt < 8; ++nt) {
            bf16x8 bfrag = w1s[(ks * 8 + nt) * 64 + lane];
            acc[nt] = __builtin_amdgcn_mfma_f32_16x16x32_bf16(afrag[ks], bfrag, acc[nt], 0, 0, 0);
        }
    }

    #pragma unroll
    for (int nt = 0; nt < 8; ++nt) {
        #pragma unroll
        for (int r = 0; r < 4; ++r) {
            int rrow = row0 + quad * 4 + r;
            if (rrow < N_NODES)
                y[(long long)rrow * HIDDEN + nt * 16 + m] = __float2bfloat16(acc[nt][r]);
        }
    }
}

// ---- 2a) convert 8 copies -> per-copy exclusive offsets (in place),
// total into cnt, plus per-block partial sums for the scan ----------------
__global__ __launch_bounds__(SCAN_BS) void scan_partial(int* __restrict__ hist8,
                                                        int* __restrict__ cnt,
                                                        int* __restrict__ block_sums)
{
    __shared__ int red[SCAN_BS / 64];
    int i = blockIdx.x * SCAN_BS + threadIdx.x;
    int total = 0;
    if (i < N_NODES) {
        int off = 0;
        #pragma unroll
        for (int c = 0; c < N_BUCKETS; ++c) {
            int h = hist8[c * HIST_STRIDE + i];
            hist8[c * HIST_STRIDE + i] = off;     // exclusive prefix over copies
            off += h;
        }
        total = off;
        cnt[i] = total;
    }
    int s = total;
    for (int off = 32; off > 0; off >>= 1) s += __shfl_down(s, off, 64);
    int wave = threadIdx.x >> 6, lane = threadIdx.x & 63;
    if (lane == 0) red[wave] = s;
    __syncthreads();
    if (threadIdx.x == 0) {
        int tt = 0;
        #pragma unroll
        for (int wv = 0; wv < SCAN_BS / 64; ++wv) tt += red[wv];
        block_sums[blockIdx.x] = tt;
    }
}

// ---- 2b) block-local exclusive scan; inline prefix over raw block_sums ----
__global__ __launch_bounds__(SCAN_BS) void scan_final(const int* __restrict__ cnt,
                                                      const int* __restrict__ block_sums,
                                                      int* __restrict__ row_ptr)
{
    __shared__ int tmp[SCAN_BS];
    __shared__ int blk_off;
    int t = threadIdx.x;
    int i = blockIdx.x * SCAN_BS + t;
    if (t == 0) {
        int s = 0;
        for (int j = 0; j < (int)blockIdx.x; ++j) s += block_sums[j];
        blk_off = s;
        if (blockIdx.x == 0) row_ptr[N_NODES] = N_EDGES;
    }
    int v = (i < N_NODES) ? cnt[i] : 0;
    tmp[t] = v;
    __syncthreads();
    for (int off = 1; off < SCAN_BS; off <<= 1) {
        int u = (t >= off) ? tmp[t - off] : 0;
        __syncthreads();
        tmp[t] += u;
        __syncthreads();
    }
    if (i < N_NODES) row_ptr[i] = tmp[t] - v + blk_off;
}

// ---- 3) scatter_det: SINGLE-PASS deterministic placement, NO atomics.
// Each edge read exactly once (13 MB coalesced) instead of the old 8x
// bucket-filtered rescan (77 MB). Scattered 8B writes merge in L2/LLC.
__global__ __launch_bounds__(256) void scatter_det(const int* __restrict__ src,
                                                   const int* __restrict__ dst,
                                                   const float* __restrict__ w,
                                                   const int* __restrict__ hist8,
                                                   const int* __restrict__ erank,
                                                   const int* __restrict__ row_ptr,
                                                   Edge* __restrict__ edges)
{
    int i = blockIdx.x * 256 + threadIdx.x;       // grid exact: 3125*256
    int d = dst[i];
    int copy = (i >> 8) & (N_BUCKETS - 1);        // == hist's hb&7
    int pos = row_ptr[d] + hist8[copy * HIST_STRIDE + d] + erank[i];
    Edge ed; ed.s = src[i]; ed.w = w[i];
    edges[pos] = ed;
}

// ---- 4) spmm1: h1 = relu(A @ y + b1); wave/node, 8-deep gather unroll -----
__global__ __launch_bounds__(256) void spmm1_kernel(const int* __restrict__ row_ptr,
                                                    const Edge* __restrict__ edges,
                                                    const __hip_bfloat16* __restrict__ y,
                                                    const float* __restrict__ b1,
                                                    __hip_bfloat16* __restrict__ h1)
{
    int node = blockIdx.x * 4 + (threadIdx.x >> 6);
    int lane = threadIdx.x & 63;
    if (node >= N_NODES) return;
    int beg = row_ptr[node];
    int end = row_ptr[node + 1];
    const __hip_bfloat162* yv = (const __hip_bfloat162*)y;
    float ax = 0.f, ay = 0.f;
    int j = beg;
    for (; j + 7 < end; j += 8) {                 // 8 gathers in flight
        Edge e0 = edges[j + 0];
        Edge e1 = edges[j + 1];
        Edge e2 = edges[j + 2];
        Edge e3 = edges[j + 3];
        Edge e4 = edges[j + 4];
        Edge e5 = edges[j + 5];
        Edge e6 = edges[j + 6];
        Edge e7 = edges[j + 7];
        __hip_bfloat162 v0 = yv[(e0.s << 6) + lane];
        __hip_bfloat162 v1 = yv[(e1.s << 6) + lane];
        __hip_bfloat162 v2 = yv[(e2.s << 6) + lane];
        __hip_bfloat162 v3 = yv[(e3.s << 6) + lane];
        __hip_bfloat162 v4 = yv[(e4.s << 6) + lane];
        __hip_bfloat162 v5 = yv[(e5.s << 6) + lane];
        __hip_bfloat162 v6 = yv[(e6.s << 6) + lane];
        __hip_bfloat162 v7 = yv[(e7.s << 6) + lane];
        ax = fmaf(e0.w, __low2float(v0), ax);  ay = fmaf(e0.w, __high2float(v0), ay);
        ax = fmaf(e1.w, __low2float(v1), ax);  ay = fmaf(e1.w, __high2float(v1), ay);
        ax = fmaf(e2.w, __low2float(v2), ax);  ay = fmaf(e2.w, __high2float(v2), ay);
        ax = fmaf(e3.w, __low2float(v3), ax);  ay = fmaf(e3.w, __high2float(v3), ay);
        ax = fmaf(e4.w, __low2float(v4), ax);  ay = fmaf(e4.w, __high2float(v4), ay);
        ax = fmaf(e5.w, __low2float(v5), ax);  ay = fmaf(e5.w, __high2float(v5), ay);
        ax = fmaf(e6.w, __low2float(v6), ax);  ay = fmaf(e6.w, __high2float(v6), ay);
        ax = fmaf(e7.w, __low2float(v7), ax);  ay = fmaf(e7.w, __high2float(v7), ay);
    }
    for (; j + 3 < end; j += 4) {
        Edge e0 = edges[j + 0];
        Edge e1 = edges[j + 1];
        Edge e2 = edges[j + 2];
        Edge e3 = edges[j + 3];
        __hip_bfloat162 v0 = yv[(e0.s << 6) + lane];
        __hip_bfloat162 v1 = yv[(e1.s << 6) + lane];
        __hip_bfloat162 v2 = yv[(e2.s << 6) + lane];
        __hip_bfloat162 v3 = yv[(e3.s << 6) + lane];
        ax = fmaf(e0.w, __low2float(v0), ax);  ay = fmaf(e0.w, __high2float(v0), ay);
        ax = fmaf(e1.w, __low2float(v1), ax);  ay = fmaf(e1.w, __high2float(v1), ay);
        ax = fmaf(e2.w, __low2float(v2), ax);  ay = fmaf(e2.w, __high2float(v2), ay);
        ax = fmaf(e3.w, __low2float(v3), ax);  ay = fmaf(e3.w, __high2float(v3), ay);
    }
    for (; j < end; ++j) {
        Edge e0 = edges[j];
        __hip_bfloat162 v0 = yv[(e0.s << 6) + lane];
        ax = fmaf(e0.w, __low2float(v0), ax);
        ay = fmaf(e0.w, __high2float(v0), ay);
    }
    float2 bv = ((const float2*)b1)[lane];
    __hip_bfloat162 hv;
    hv.x = __float2bfloat16(fmaxf(ax + bv.x, 0.f));
    hv.y = __float2bfloat16(fmaxf(ay + bv.y, 0.f));
    ((__hip_bfloat162*)h1)[(node << 6) + lane] = hv;
}

// ---- 5) gemm2: g = h1 @ W2; 8 rows/block amortize the W2 pass -------------
#define G2_ROWS 8
__global__ __launch_bounds__(64) void gemm2_kernel(const __hip_bfloat16* __restrict__ h1,
                                                   const float* __restrict__ W2,
                                                   __hip_bfloat16* __restrict__ g)
{
    __shared__ float xs[G2_ROWS][HIDDEN];
    int row0 = blockIdx.x * G2_ROWS;
    int t = threadIdx.x;
    #pragma unroll
    for (int r = 0; r < G2_ROWS; ++r) {
        xs[r][t]      = __bfloat162float(h1[(long long)(row0 + r) * HIDDEN + t]);
        xs[r][t + 64] = __bfloat162float(h1[(long long)(row0 + r) * HIDDEN + t + 64]);
    }
    __syncthreads();
    if (t >= OUT_DIM) return;
    float acc[G2_ROWS];
    #pragma unroll
    for (int r = 0; r < G2_ROWS; ++r) acc[r] = 0.f;
    #pragma unroll 4
    for (int k = 0; k < HIDDEN; ++k) {
        float wv = W2[k * OUT_DIM + t];
        #pragma unroll
        for (int r = 0; r < G2_ROWS; ++r)
            acc[r] = fmaf(xs[r][k], wv, acc[r]);
    }
    #pragma unroll
    for (int r = 0; r < G2_ROWS; ++r)
        g[((row0 + r) << 6) + t] = __float2bfloat16(acc[r]);   // padded row
}

// ---- 6) spmm2: out = A @ g + b2; wave/node, 40 active lanes; g row is one
// aligned 128B line per edge gather; 8-deep gather unroll ------------------
__global__ __launch_bounds__(256) void spmm2_kernel(const int* __restrict__ row_ptr,
                                                    const Edge* __restrict__ edges,
                                                    const __hip_bfloat16* __restrict__ g,
                                                    const float* __restrict__ b2,
                                                    float* __restrict__ out)
{
    int node = blockIdx.x * 4 + (threadIdx.x >> 6);
    int lane = threadIdx.x & 63;
    if (node >= N_NODES) return;
    if (lane >= OUT_DIM) return;
    int beg = row_ptr[node];
    int end = row_ptr[node + 1];
    float acc = 0.f;
    int j = beg;
    for (; j + 7 < end; j += 8) {
        Edge e0 = edges[j + 0];
        Edge e1 = edges[j + 1];
        Edge e2 = edges[j + 2];
        Edge e3 = edges[j + 3];
        Edge e4 = edges[j + 4];
        Edge e5 = edges[j + 5];
        Edge e6 = edges[j + 6];
        Edge e7 = edges[j + 7];
        float v0 = __bfloat162float(g[(e0.s << 6) + lane]);
        float v1 = __bfloat162float(g[(e1.s << 6) + lane]);
        float v2 = __bfloat162float(g[(e2.s << 6) + lane]);
        float v3 = __bfloat162float(g[(e3.s << 6) + lane]);
        float v4 = __bfloat162float(g[(e4.s << 6) + lane]);
        float v5 = __bfloat162float(g[(e5.s << 6) + lane]);
        float v6 = __bfloat162float(g[(e6.s << 6) + lane]);
        float v7 = __bfloat162float(g[(e7.s << 6) + lane]);
        acc = fmaf(e0.w, v0, acc);
        acc = fmaf(e1.w, v1, acc);
        acc = fmaf(e2.w, v2, acc);
        acc = fmaf(e3.w, v3, acc);
        acc = fmaf(e4.w, v4, acc);
        acc = fmaf(e5.w, v5, acc);
        acc = fmaf(e6.w, v6, acc);
        acc = fmaf(e7.w, v7, acc);
    }
    for (; j + 3 < end; j += 4) {
        Edge e0 = edges[j + 0];
        Edge e1 = edges[j + 1];
        Edge e2 = edges[j + 2];
        Edge e3 = edges[j + 3];
        float v0 = __bfloat162float(g[(e0.s << 6) + lane]);
        float v1 = __bfloat162float(g[(e1.s << 6) + lane]);
        float v2 = __bfloat162float(g[(e2.s << 6) + lane]);
        float v3 = __bfloat162float(g[(e3.s << 6) + lane]);
        acc = fmaf(e0.w, v0, acc);
        acc = fmaf(e1.w, v1, acc);
        acc = fmaf(e2.w, v2, acc);
        acc = fmaf(e3.w, v3, acc);
    }
    for (; j < end; ++j) {
        Edge e0 = edges[j];
        acc = fmaf(e0.w, __bfloat162float(g[(e0.s << 6) + lane]), acc);
    }
    out[(long long)node * OUT_DIM + lane] = acc + b2[lane];
}

extern "C" void kernel_launch(void* const* d_in, const int* in_sizes, int n_in,
                              void* d_out, int out_size, void* d_ws, size_t ws_size,
                              hipStream_t stream)
{
    const float* x    = (const float*)d_in[0];
    const int*   esrc = (const int*)  d_in[1];
    const int*   edst = (const int*)  d_in[2];
    const float* ew   = (const float*)d_in[3];
    const float* W1   = (const float*)d_in[4];
    const float* b1   = (const float*)d_in[5];
    const float* W2   = (const float*)d_in[6];
    const float* b2   = (const float*)d_in[7];
    float* out = (float*)d_out;

    // workspace layout (~38 MB); g aliases y (y is dead after spmm1)
    __hip_bfloat16* y  = (__hip_bfloat16*)d_ws;                  // 12.8 MB
    __hip_bfloat16* g  = y;                                      // 6.4 MB (aliased)
    __hip_bfloat16* h1 = y + (size_t)N_NODES * HIDDEN;           // 12.8 MB
    Edge* edges     = (Edge*)(h1 + (size_t)N_NODES * HIDDEN);    // 6.4 MB
    int* hist8      = (int*)(edges + N_EDGES);                   // 1.6 MB
    int* erank      = hist8 + N_BUCKETS * HIST_STRIDE;           // 3.2 MB
    int* cnt        = erank + N_EDGES;                           // 200 KB
    int* row_ptr    = cnt + 50176;                               // 50001 (pad 50176)
    int* block_sums = row_ptr + 50176;                           // 64 ints

    // CSR build + gemm1 co-run (interleaved 1:4 so MFMA overlaps atomics)
    hipMemsetAsync(hist8, 0, N_BUCKETS * HIST_STRIDE * sizeof(int), stream);
    hist_gemm1<<<HG_GRID, 256, 0, stream>>>(edst, hist8, erank, x, W1, y);
    scan_partial<<<SCAN_BLOCKS, SCAN_BS, 0, stream>>>(hist8, cnt, block_sums);
    scan_final<<<SCAN_BLOCKS, SCAN_BS, 0, stream>>>(cnt, block_sums, row_ptr);
    scatter_det<<<N_EDGES / 256, 256, 0, stream>>>(esrc, edst, ew, hist8,
                                                   erank, row_ptr, edges);

    // h1 = relu(A @ y + b1)
    spmm1_kernel<<<N_NODES / 4, 256, 0, stream>>>(row_ptr, edges, y, b1, h1);
    // g = h1 @ W2 (8-row W2 amortization; padded g rows)
    gemm2_kernel<<<N_NODES / G2_ROWS, 64, 0, stream>>>(h1, W2, g);
    // out = A @ g + b2
    spmm2_kernel<<<(N_NODES + 3) / 4, 256, 0, stream>>>(row_ptr, edges, g, b2, out);
}